// Round 10
// baseline (373.394 us; speedup 1.0000x reference)
//
#include <hip/hip_runtime.h>

// LSS-FPN round 20: T2 bank-conflict swizzle on conv LDS (X and W).
// 32B-row layout had bank-starts {0,8,16,24} (4.7 extra cyc/ds_read_b128,
// 6.25M conflict cycles in conv6d). Fix: byte ^= (row&4)<<2, applied as
// permuted global SOURCE (lane ^= (lane>>3)&1) + XOR on the READ address;
// LDS dest stays linear (global_load_lds rule). Everything else = R19.

#define FH_ 16
#define FW_ 44
#define SP_ 704
#define XSTR 960         // xt rows per image (incl. halo slack)
#define NIMG 6
#define CIN 512
#define DCH 112
#define CCTX 80
#define NXY 128
#define NVOX (NXY * NXY)
#define NPTS (NIMG * DCH * SP_)
#define CHUNK 64

#define NKC6 8           // kc steps for K-split x4 conv (16 ci each)
#define HCHK 360448      // fp16 partial chunk: 704*512 halves
#define CIP 40           // padded LDS k-stride for gemm1x1 (shorts)

typedef unsigned short u16;
typedef unsigned int u32;
typedef __attribute__((ext_vector_type(8))) short bf16x8;
typedef __attribute__((ext_vector_type(4))) short s16x4;
typedef __attribute__((ext_vector_type(4))) float f32x4;
typedef __attribute__((ext_vector_type(16))) float f32x16;

__device__ __forceinline__ float bf2f(u16 b) {
    union { unsigned u; float f; } v; v.u = ((unsigned)b) << 16; return v.f;
}
__device__ __forceinline__ u16 f2bf(float f) {
    union { float f; unsigned u; } v; v.f = f;
    unsigned r = v.u + 0x7fffu + ((v.u >> 16) & 1u);   // RTNE
    return (u16)(r >> 16);
}
__device__ __forceinline__ int spad_of(int s) {
    return (s / 44) * 46 + (s % 44) + 47;
}
__device__ __forceinline__ void gld_lds16(const void* gsrc, void* ldst) {
    __builtin_amdgcn_global_load_lds(
        (const __attribute__((address_space(1))) u32*)gsrc,
        (__attribute__((address_space(3))) u32*)ldst, 16, 0, 0);
}
// fp16 partial chunk c in [0,24): chunks 0-5 in dead whiB region (pA),
// chunks 6-23 in post-conv tail region (pB).
__device__ __forceinline__ _Float16* chunkc(_Float16* pA, _Float16* pB, int c) {
    return (c < 6) ? (pA + (size_t)c * HCHK) : (pB + (size_t)(c - 6) * HCHK);
}

// ---------------- zero fill ---------------------------------------------------
__global__ void zero_k(float4* __restrict__ p, long n4) {
    long i = (long)blockIdx.x * blockDim.x + threadIdx.x;
    if (i < n4) p[i] = make_float4(0.f, 0.f, 0.f, 0.f);
}

// ------- src fp32 [n][ci][704] -> xt2 bf16 chunked [n][32][960][16] ----------
__global__ void src_to_xt_k(const float* __restrict__ src, short* __restrict__ xt) {
    int e = blockIdx.x * 256 + threadIdx.x;
    if (e >= NIMG * SP_ * CIN) return;
    int ci = e & 511;
    int r = e >> 9;
    int s = r % SP_, n = r / SP_;
    float v = src[((size_t)n * CIN + ci) * SP_ + s];
    xt[(((size_t)n * 32 + (ci >> 4)) * XSTR + spad_of(s)) * 16 + (ci & 15)] = (short)f2bf(v);
}

// ------- weight convert: fp32 [co][ci][9] -> W2 bf16 [kc][t][co][16] ---------
// dual: two tensors in one dispatch (grid 2 * CIN*CIN / 256)
__global__ void wsplit2_k(const float* __restrict__ wA, short* __restrict__ oA,
                          const float* __restrict__ wB, short* __restrict__ oB) {
    int i = blockIdx.x * 256 + threadIdx.x;
    if (i >= 2 * CIN * CIN) return;
    const int e = i & (CIN * CIN - 1);
    const float* __restrict__ w = (i < CIN * CIN) ? wA : wB;
    short* __restrict__ o = (i < CIN * CIN) ? oA : oB;
    const int co = e >> 9, ci = e & 511;
    const float* wp = w + (size_t)e * 9;
#pragma unroll
    for (int t = 0; t < 9; ++t)
        o[((((size_t)(ci >> 4) * 9) + t) * CIN + co) * 16 + (ci & 15)] = (short)f2bf(wp[t]);
}

// ------- postprep: 1x1 weight converts + zero of cnt/off/cur/accT ------------
#define ZBASE 9536000                     // O_CNT (float index, /4 aligned)
#define ZLEN4 339972                      // (10,895,888 - 9,536,000) / 4
__global__ void postprep_k(const float* __restrict__ wd, short* __restrict__ od,
                           const float* __restrict__ wc, short* __restrict__ oc,
                           float4* __restrict__ zp) {
    const int NW = (DCH + CCTX) * CIN;    // 98,304
    int i = blockIdx.x * 256 + threadIdx.x;
    if (i < NW) {
        if (i < DCH * CIN) od[i] = (short)f2bf(wd[i]);
        else oc[i - DCH * CIN] = (short)f2bf(wc[i - DCH * CIN]);
    } else {
        int j = i - NW;
        if (j < ZLEN4) zp[j] = make_float4(0.f, 0.f, 0.f, 0.f);
    }
}

// ---------------- conv3x3, K-split x4, gld_lds staging + T2 swizzle ----------
// grid 576: bid = (n*6+sb)*16 + (cb*4+q). Block: 128sp x 128co x 128ci.
// 4 waves (mw,nw) each 64sp x 64co (M2N2). fp16 partial out [s][512co].
// LDS swizzle: byte ^= (row&4)<<2 -> source perm sl = lane^((lane>>3)&1),
// read addr ^= ((row>>2)&1)*8 shorts.
__global__ __launch_bounds__(256, 3) void conv6_k(
    const short* __restrict__ xt2, const short* __restrict__ w2,
    _Float16* __restrict__ pA, _Float16* __restrict__ pB)
{
    __shared__ short Xs[256 * 16];        // 8,192 B (232 rows used + slack)
    __shared__ short Wsh[1152 * 16];      // 36,864 B
    const int tid = threadIdx.x;
    const int lane = tid & 63, wave = tid >> 6;
    const int l31 = lane & 31, lh = lane >> 5;
    const int mw = wave >> 1, nw = wave & 1;
    const int sl = lane ^ ((lane >> 3) & 1);      // swizzled source lane

    const int bid = blockIdx.x;
    const int c16 = bid & 15;
    const int cb = c16 >> 2, q = c16 & 3;
    const int rest = bid >> 4;
    const int n = rest / 6, sb = rest - (rest / 6) * 6;

    const int s0 = sb * 128;
    const int co0 = cb * 128;
    const int base = spad_of(s0) - 47;

    const short* __restrict__ xq = xt2 + (((size_t)n * 32 + q * 8) * XSTR + base) * 16;
    const short* __restrict__ wq = w2 + (((size_t)(q * 8) * 9) * CIN + co0) * 16;

    int sloc[2];
#pragma unroll
    for (int mf = 0; mf < 2; ++mf)
        sloc[mf] = spad_of(s0 + mw * 64 + mf * 32 + l31) - base;
    const int wswz = (lh ^ ((l31 >> 2) & 1)) * 8; // W read swizzle (lane-const)

    const f32x16 z16 = {0.f,0.f,0.f,0.f,0.f,0.f,0.f,0.f,
                        0.f,0.f,0.f,0.f,0.f,0.f,0.f,0.f};
    f32x16 acc[2][2];
    acc[0][0] = z16; acc[0][1] = z16; acc[1][0] = z16; acc[1][1] = z16;

#define STAGE6(KC) do {                                                         \
    const short* xc = xq + (size_t)(KC) * (XSTR * 16) + sl * 8;                 \
    const short* wc = wq + (size_t)(KC) * (9 * CIN * 16) + sl * 8;              \
    _Pragma("unroll")                                                           \
    for (int i = 0; i < 11; ++i) {                                              \
        const int sg = wave + 4 * i;                                            \
        if (sg < 8) {                                                           \
            gld_lds16(xc + sg * 512, &Xs[sg * 512]);                            \
        } else {                                                                \
            const int j = sg - 8, t = j >> 2, s4 = j & 3;                       \
            gld_lds16(wc + t * (CIN * 16) + s4 * 512, &Wsh[sg * 512 - 4096]);   \
        }                                                                       \
    }                                                                           \
} while (0)

    STAGE6(0);
    __syncthreads();

    constexpr int OFF[9] = {-47, -46, -45, -1, 0, 1, 45, 46, 47};
    for (int kc = 0; kc < NKC6; ++kc) {
#pragma unroll
        for (int t9 = 0; t9 < 9; ++t9) {
            const int off = OFF[t9];
            const int rw0 = sloc[0] + off, rw1 = sloc[1] + off;
            const int wr0 = t9 * 128 + nw * 64 + l31;
            bf16x8 a0 = *(const bf16x8*)&Xs[rw0 * 16 + ((lh ^ ((rw0 >> 2) & 1)) * 8)];
            bf16x8 a1 = *(const bf16x8*)&Xs[rw1 * 16 + ((lh ^ ((rw1 >> 2) & 1)) * 8)];
            bf16x8 b0 = *(const bf16x8*)&Wsh[wr0 * 16 + wswz];
            bf16x8 b1 = *(const bf16x8*)&Wsh[(wr0 + 32) * 16 + wswz];
            acc[0][0] = __builtin_amdgcn_mfma_f32_32x32x16_bf16(a0, b0, acc[0][0], 0, 0, 0);
            acc[0][1] = __builtin_amdgcn_mfma_f32_32x32x16_bf16(a0, b1, acc[0][1], 0, 0, 0);
            acc[1][0] = __builtin_amdgcn_mfma_f32_32x32x16_bf16(a1, b0, acc[1][0], 0, 0, 0);
            acc[1][1] = __builtin_amdgcn_mfma_f32_32x32x16_bf16(a1, b1, acc[1][1], 0, 0, 0);
        }
        __syncthreads();
        if (kc + 1 < NKC6) {
            STAGE6(kc + 1);
            __syncthreads();
        }
    }
#undef STAGE6

    _Float16* __restrict__ Pc = chunkc(pA, pB, q * 6 + n);
#pragma unroll
    for (int mf = 0; mf < 2; ++mf) {
        const int spb = mw * 64 + mf * 32 + 4 * lh;
#pragma unroll
        for (int r = 0; r < 16; ++r) {
            const int sg = s0 + spb + (r & 3) + 8 * (r >> 2);
            if (sg < SP_) {
                const size_t ro = (size_t)sg * 512 + co0 + nw * 64 + l31;
                Pc[ro] = (_Float16)acc[mf][0][r];
                Pc[ro + 32] = (_Float16)acc[mf][1][r];
            }
        }
    }
}

// ---------------- dual conv (c1+d1), K-split x2 per layer, swizzled ----------
// grid 576: bid = (n*6+sb)*16 + (cb*4 + layer*2 + q); q in [0,2) selects
// 256-ci half; NKC=16. Partial chunk c = layer*12 + q*6 + n (24 chunks).
__global__ __launch_bounds__(256, 3) void conv6d_k(
    const short* __restrict__ xt2, const short* __restrict__ wA,
    const short* __restrict__ wB,
    _Float16* __restrict__ pA, _Float16* __restrict__ pB)
{
    __shared__ short Xs[256 * 16];
    __shared__ short Wsh[1152 * 16];
    const int tid = threadIdx.x;
    const int lane = tid & 63, wave = tid >> 6;
    const int l31 = lane & 31, lh = lane >> 5;
    const int mw = wave >> 1, nw = wave & 1;
    const int sl = lane ^ ((lane >> 3) & 1);      // swizzled source lane

    const int bid = blockIdx.x;
    const int c16 = bid & 15;
    const int cb = c16 >> 2;
    const int layer = (c16 >> 1) & 1, q = c16 & 1;
    const int rest = bid >> 4;
    const int n = rest / 6, sb = rest - (rest / 6) * 6;

    const int s0 = sb * 128;
    const int co0 = cb * 128;
    const int base = spad_of(s0) - 47;

    const short* __restrict__ w2 = layer ? wB : wA;
    const short* __restrict__ xq = xt2 + (((size_t)n * 32 + q * 16) * XSTR + base) * 16;
    const short* __restrict__ wq = w2 + (((size_t)(q * 16) * 9) * CIN + co0) * 16;

    int sloc[2];
#pragma unroll
    for (int mf = 0; mf < 2; ++mf)
        sloc[mf] = spad_of(s0 + mw * 64 + mf * 32 + l31) - base;
    const int wswz = (lh ^ ((l31 >> 2) & 1)) * 8;

    const f32x16 z16 = {0.f,0.f,0.f,0.f,0.f,0.f,0.f,0.f,
                        0.f,0.f,0.f,0.f,0.f,0.f,0.f,0.f};
    f32x16 acc[2][2];
    acc[0][0] = z16; acc[0][1] = z16; acc[1][0] = z16; acc[1][1] = z16;

#define STAGE6D(KC) do {                                                        \
    const short* xc = xq + (size_t)(KC) * (XSTR * 16) + sl * 8;                 \
    const short* wc = wq + (size_t)(KC) * (9 * CIN * 16) + sl * 8;              \
    _Pragma("unroll")                                                           \
    for (int i = 0; i < 11; ++i) {                                              \
        const int sg = wave + 4 * i;                                            \
        if (sg < 8) {                                                           \
            gld_lds16(xc + sg * 512, &Xs[sg * 512]);                            \
        } else {                                                                \
            const int j = sg - 8, t = j >> 2, s4 = j & 3;                       \
            gld_lds16(wc + t * (CIN * 16) + s4 * 512, &Wsh[sg * 512 - 4096]);   \
        }                                                                       \
    }                                                                           \
} while (0)

    STAGE6D(0);
    __syncthreads();

    constexpr int OFF[9] = {-47, -46, -45, -1, 0, 1, 45, 46, 47};
    for (int kc = 0; kc < 16; ++kc) {
#pragma unroll
        for (int t9 = 0; t9 < 9; ++t9) {
            const int off = OFF[t9];
            const int rw0 = sloc[0] + off, rw1 = sloc[1] + off;
            const int wr0 = t9 * 128 + nw * 64 + l31;
            bf16x8 a0 = *(const bf16x8*)&Xs[rw0 * 16 + ((lh ^ ((rw0 >> 2) & 1)) * 8)];
            bf16x8 a1 = *(const bf16x8*)&Xs[rw1 * 16 + ((lh ^ ((rw1 >> 2) & 1)) * 8)];
            bf16x8 b0 = *(const bf16x8*)&Wsh[wr0 * 16 + wswz];
            bf16x8 b1 = *(const bf16x8*)&Wsh[(wr0 + 32) * 16 + wswz];
            acc[0][0] = __builtin_amdgcn_mfma_f32_32x32x16_bf16(a0, b0, acc[0][0], 0, 0, 0);
            acc[0][1] = __builtin_amdgcn_mfma_f32_32x32x16_bf16(a0, b1, acc[0][1], 0, 0, 0);
            acc[1][0] = __builtin_amdgcn_mfma_f32_32x32x16_bf16(a1, b0, acc[1][0], 0, 0, 0);
            acc[1][1] = __builtin_amdgcn_mfma_f32_32x32x16_bf16(a1, b1, acc[1][1], 0, 0, 0);
        }
        __syncthreads();
        if (kc + 1 < 16) {
            STAGE6D(kc + 1);
            __syncthreads();
        }
    }
#undef STAGE6D

    _Float16* __restrict__ Pc = chunkc(pA, pB, layer * 12 + q * 6 + n);
#pragma unroll
    for (int mf = 0; mf < 2; ++mf) {
        const int spb = mw * 64 + mf * 32 + 4 * lh;
#pragma unroll
        for (int r = 0; r < 16; ++r) {
            const int sg = s0 + spb + (r & 3) + 8 * (r >> 2);
            if (sg < SP_) {
                const size_t ro = (size_t)sg * 512 + co0 + nw * 64 + l31;
                Pc[ro] = (_Float16)acc[mf][0][r];
                Pc[ro + 32] = (_Float16)acc[mf][1][r];
            }
        }
    }
}

// ---------------- combine: relu(sum of 4 chunks) -> bf16 chunked xt ----------
__global__ __launch_bounds__(256) void combine6_k(
    _Float16* __restrict__ pA, _Float16* __restrict__ pB, short* __restrict__ xout)
{
    const int i = blockIdx.x * 256 + threadIdx.x;
    if (i >= NIMG * SP_ * CIN / 4) return;
    const int e = i * 4;
    const int n = e / (SP_ * CIN);
    const int r = e - n * (SP_ * CIN);
    const int s = r >> 9, co = r & 511;
    union h4 { s16x4 s; _Float16 h[4]; };
    float v[4] = {0.f, 0.f, 0.f, 0.f};
#pragma unroll
    for (int q = 0; q < 4; ++q) {
        const _Float16* c = chunkc(pA, pB, q * 6 + n);
        h4 u; u.s = *(const s16x4*)(c + r);
#pragma unroll
        for (int j = 0; j < 4; ++j) v[j] += (float)u.h[j];
    }
    s16x4 o;
#pragma unroll
    for (int j = 0; j < 4; ++j) o[j] = (short)f2bf(fmaxf(v[j], 0.f));
    *(s16x4*)&xout[(((size_t)n * 32 + (co >> 4)) * XSTR + spad_of(s)) * 16 + (co & 15)] = o;
}

// dual combine: layer 0 -> o0 (c1/xt1), layer 1 -> o1 (d1/xt2); 2 chunks each
__global__ __launch_bounds__(256) void combine6d_k(
    _Float16* __restrict__ pA, _Float16* __restrict__ pB,
    short* __restrict__ o0, short* __restrict__ o1)
{
    const int i = blockIdx.x * 256 + threadIdx.x;
    if (i >= 2 * NIMG * SP_ * CIN / 4) return;
    const int L = i / (NIMG * SP_ * CIN / 4);
    const int j0 = i - L * (NIMG * SP_ * CIN / 4);
    const int e = j0 * 4;
    const int n = e / (SP_ * CIN);
    const int r = e - n * (SP_ * CIN);
    const int s = r >> 9, co = r & 511;
    union h4 { s16x4 s; _Float16 h[4]; };
    float v[4] = {0.f, 0.f, 0.f, 0.f};
#pragma unroll
    for (int q = 0; q < 2; ++q) {
        const _Float16* c = chunkc(pA, pB, L * 12 + q * 6 + n);
        h4 u; u.s = *(const s16x4*)(c + r);
#pragma unroll
        for (int j = 0; j < 4; ++j) v[j] += (float)u.h[j];
    }
    s16x4 o;
#pragma unroll
    for (int j = 0; j < 4; ++j) o[j] = (short)f2bf(fmaxf(v[j], 0.f));
    short* __restrict__ xout = L ? o1 : o0;
    *(s16x4*)&xout[(((size_t)n * 32 + (co >> 4)) * XSTR + spad_of(s)) * 16 + (co & 15)] = o;
}

// ------- merged 1x1 convs (d2 + c2) as GEMM, 64sp tiles, fused softmax -------
// grid (11, 2, 6): y=0 -> depth head (softmax over 112 ch, writes probs),
//                  y=1 -> context head (NCO=80, bias only).
__global__ __launch_bounds__(256, 2) void gemm1x1d_k(
    const short* __restrict__ xA, const short* __restrict__ wA,
    const float* __restrict__ bA, float* __restrict__ oA,
    const short* __restrict__ xB, const short* __restrict__ wB,
    const float* __restrict__ bB, float* __restrict__ oB)
{
    const int sel = blockIdx.y;
    const short* __restrict__ xtin = sel ? xB : xA;
    const short* __restrict__ wb   = sel ? wB : wA;
    const float* __restrict__ bias = sel ? bB : bA;
    float* __restrict__ outT       = sel ? oB : oA;
    const int nst = sel ? (CCTX / 16) : (DCH / 16);   // 5 or 7
    const int nco = nst * 16;

    __shared__ short Wb[DCH * CIP];
    const int tid = threadIdx.x;
    const int s0 = blockIdx.x * 64, n = blockIdx.z;
    const int lane = tid & 63, wave = tid >> 6;
    const int kg = lane >> 4, lrow = lane & 15;
    const int swave = s0 + wave * 16;

    const int arow = spad_of(swave + lrow);

    const f32x4 zero4 = {0.f, 0.f, 0.f, 0.f};
    f32x4 acc[7];
#pragma unroll
    for (int ns = 0; ns < 7; ++ns) acc[ns] = zero4;

    const short* xb = xtin + (size_t)n * 32 * XSTR * 16;

    for (int kc = 0; kc < 16; ++kc) {
        __syncthreads();
#pragma unroll
        for (int it = 0; it < 2; ++it) {
            int q = it * 256 + tid;
            if (q < nco * 4) {
                int co = q >> 2, p = q & 3;
                *(bf16x8*)&Wb[co * CIP + p * 8] =
                    *(const bf16x8*)(wb + (size_t)co * CIN + kc * 32 + p * 8);
            }
        }
        __syncthreads();
        const int kcc = 2 * kc + (kg >> 1);
        bf16x8 a = *(const bf16x8*)(xb + ((size_t)kcc * XSTR + arow) * 16 + (kg & 1) * 8);
#pragma unroll
        for (int ns = 0; ns < 7; ++ns) {
            if (ns < nst) {
                int co = ns * 16 + lrow;
                bf16x8 b = *(const bf16x8*)&Wb[co * CIP + kg * 8];
                acc[ns] = __builtin_amdgcn_mfma_f32_16x16x32_bf16(a, b, acc[ns], 0, 0, 0);
            }
        }
    }
    // bias
#pragma unroll
    for (int ns = 0; ns < 7; ++ns) {
        if (ns < nst) {
            const float bv = bias[ns * 16 + lrow];
#pragma unroll
            for (int r = 0; r < 4; ++r) acc[ns][r] += bv;
        }
    }
    // fused softmax for the depth head (nst==7, exactly 112 channels:
    // 7 regs x 16 lanes of this kg group hold one pixel's channels)
    if (sel == 0) {
#pragma unroll
        for (int r = 0; r < 4; ++r) {
            float m = acc[0][r];
#pragma unroll
            for (int ns = 1; ns < 7; ++ns) m = fmaxf(m, acc[ns][r]);
#pragma unroll
            for (int o = 8; o; o >>= 1) m = fmaxf(m, __shfl_xor(m, o));
            float ssum = 0.f;
#pragma unroll
            for (int ns = 0; ns < 7; ++ns) {
                float ev = __expf(acc[ns][r] - m);
                acc[ns][r] = ev; ssum += ev;
            }
#pragma unroll
            for (int o = 8; o; o >>= 1) ssum += __shfl_xor(ssum, o);
            const float inv = 1.f / ssum;
#pragma unroll
            for (int ns = 0; ns < 7; ++ns) acc[ns][r] *= inv;
        }
    }
#pragma unroll
    for (int ns = 0; ns < 7; ++ns) {
        if (ns < nst) {
#pragma unroll
            for (int r = 0; r < 4; ++r) {
                const int sg = swave + kg * 4 + r;
                const int co = ns * 16 + lrow;
                outT[((size_t)n * SP_ + sg) * nco + co] = acc[ns][r];
            }
        }
    }
}

// ---------------- per-camera geometry constants (fp64, closed-form) ----------
__device__ __forceinline__ void inv4(const double* M, double* inv) {
    inv[0]  =  M[5]*M[10]*M[15] - M[5]*M[11]*M[14] - M[9]*M[6]*M[15] + M[9]*M[7]*M[14] + M[13]*M[6]*M[11] - M[13]*M[7]*M[10];
    inv[4]  = -M[4]*M[10]*M[15] + M[4]*M[11]*M[14] + M[8]*M[6]*M[15] - M[8]*M[7]*M[14] - M[12]*M[6]*M[11] + M[12]*M[7]*M[10];
    inv[8]  =  M[4]*M[9]*M[15]  - M[4]*M[11]*M[13] - M[8]*M[5]*M[15] + M[8]*M[7]*M[13] + M[12]*M[5]*M[11] - M[12]*M[7]*M[9];
    inv[12] = -M[4]*M[9]*M[14]  + M[4]*M[10]*M[13] + M[8]*M[5]*M[14] - M[8]*M[6]*M[13] - M[12]*M[5]*M[10] + M[12]*M[6]*M[9];
    inv[1]  = -M[1]*M[10]*M[15] + M[1]*M[11]*M[14] + M[9]*M[2]*M[15] - M[9]*M[3]*M[14] - M[13]*M[2]*M[11] + M[13]*M[3]*M[10];
    inv[5]  =  M[0]*M[10]*M[15] - M[0]*M[11]*M[14] - M[8]*M[2]*M[15] + M[8]*M[3]*M[14] + M[12]*M[2]*M[11] - M[12]*M[3]*M[10];
    inv[9]  = -M[0]*M[9]*M[15]  + M[0]*M[11]*M[13] + M[8]*M[1]*M[15] - M[8]*M[3]*M[13] - M[12]*M[1]*M[11] + M[12]*M[3]*M[9];
    inv[13] =  M[0]*M[9]*M[14]  - M[0]*M[10]*M[13] - M[8]*M[1]*M[14] + M[8]*M[2]*M[13] + M[12]*M[1]*M[10] - M[12]*M[2]*M[9];
    inv[2]  =  M[1]*M[6]*M[15]  - M[1]*M[7]*M[14]  - M[5]*M[2]*M[15] + M[5]*M[3]*M[14] + M[13]*M[2]*M[7]  - M[13]*M[3]*M[6];
    inv[6]  = -M[0]*M[6]*M[15]  + M[0]*M[7]*M[14]  + M[4]*M[2]*M[15] - M[4]*M[3]*M[14] - M[12]*M[2]*M[7]  + M[12]*M[3]*M[6];
    inv[10] =  M[0]*M[5]*M[15]  - M[0]*M[7]*M[13]  - M[4]*M[1]*M[15] + M[4]*M[3]*M[13] + M[12]*M[1]*M[7]  - M[12]*M[3]*M[5];
    inv[14] = -M[0]*M[5]*M[14]  + M[0]*M[6]*M[13]  + M[4]*M[1]*M[14] - M[4]*M[2]*M[13] - M[12]*M[1]*M[6]  + M[12]*M[2]*M[5];
    inv[3]  = -M[1]*M[6]*M[11]  + M[1]*M[7]*M[10]  + M[5]*M[2]*M[11] - M[5]*M[3]*M[10] - M[9]*M[2]*M[7]   + M[9]*M[3]*M[6];
    inv[7]  =  M[0]*M[6]*M[11]  - M[0]*M[7]*M[10]  - M[4]*M[2]*M[11] + M[4]*M[3]*M[10] + M[8]*M[2]*M[7]   - M[8]*M[3]*M[6];
    inv[11] = -M[0]*M[5]*M[11]  + M[0]*M[7]*M[9]   + M[4]*M[1]*M[11] - M[4]*M[3]*M[9]  - M[8]*M[1]*M[7]   + M[8]*M[3]*M[5];
    inv[15] =  M[0]*M[5]*M[10]  - M[0]*M[6]*M[9]   - M[4]*M[1]*M[10] + M[4]*M[2]*M[9]  + M[8]*M[1]*M[6]   - M[8]*M[2]*M[5];
    double det = M[0]*inv[0] + M[1]*inv[4] + M[2]*inv[8] + M[3]*inv[12];
    double id = 1.0 / det;
#pragma unroll
    for (int i = 0; i < 16; ++i) inv[i] *= id;
}

__global__ void geom_setup_k(const float* __restrict__ s2e, const float* __restrict__ intrin,
                             const float* __restrict__ ida, const float* __restrict__ bda,
                             double* __restrict__ gc)
{
    const int n = threadIdx.x;
    if (n >= NIMG) return;
    double M[16], Iv[16];
#pragma unroll
    for (int i = 0; i < 16; ++i) M[i] = (double)ida[n * 16 + i];
    inv4(M, Iv);
    double R[3][3], tv[3];
#pragma unroll
    for (int r = 0; r < 3; ++r) {
#pragma unroll
        for (int c = 0; c < 3; ++c) R[r][c] = Iv[r * 4 + c];
        tv[r] = Iv[r * 4 + 3];
    }
    double K[3][3];
#pragma unroll
    for (int r = 0; r < 3; ++r)
#pragma unroll
        for (int c = 0; c < 3; ++c) K[r][c] = (double)intrin[n * 16 + r * 4 + c];
    double det = K[0][0] * (K[1][1] * K[2][2] - K[1][2] * K[2][1])
               - K[0][1] * (K[1][0] * K[2][2] - K[1][2] * K[2][0])
               + K[0][2] * (K[1][0] * K[2][1] - K[1][1] * K[2][0]);
    double id = 1.0 / det;
    double Ki[3][3];
    Ki[0][0] = (K[1][1] * K[2][2] - K[1][2] * K[2][1]) * id;
    Ki[0][1] = (K[0][2] * K[2][1] - K[0][1] * K[2][2]) * id;
    Ki[0][2] = (K[0][1] * K[1][2] - K[0][2] * K[1][1]) * id;
    Ki[1][0] = (K[1][2] * K[2][0] - K[1][0] * K[2][2]) * id;
    Ki[1][1] = (K[0][0] * K[2][2] - K[0][2] * K[2][0]) * id;
    Ki[1][2] = (K[0][2] * K[1][0] - K[0][0] * K[1][2]) * id;
    Ki[2][0] = (K[1][0] * K[2][1] - K[1][1] * K[2][0]) * id;
    Ki[2][1] = (K[0][1] * K[2][0] - K[0][0] * K[2][1]) * id;
    Ki[2][2] = (K[0][0] * K[1][1] - K[0][1] * K[1][0]) * id;
    double A[3][3], bv[3];
#pragma unroll
    for (int r = 0; r < 3; ++r) {
#pragma unroll
        for (int c = 0; c < 3; ++c)
            A[r][c] = Ki[r][0] * R[0][c] + Ki[r][1] * R[1][c] + Ki[r][2] * R[2][c];
        bv[r] = Ki[r][0] * tv[0] + Ki[r][1] * tv[1] + Ki[r][2] * tv[2];
    }
    double* g = gc + n * 24;
#pragma unroll
    for (int r = 0; r < 3; ++r)
#pragma unroll
        for (int c = 0; c < 3; ++c) g[r * 3 + c] = A[r][c];
#pragma unroll
    for (int r = 0; r < 3; ++r) g[9 + r] = bv[r];
#pragma unroll
    for (int r = 0; r < 3; ++r)
#pragma unroll
        for (int c = 0; c < 4; ++c) {
            double acc = 0.0;
#pragma unroll
            for (int k = 0; k < 4; ++k)
                acc += (double)bda[r * 4 + k] * (double)s2e[n * 16 + k * 4 + c];
            g[12 + r * 4 + c] = acc;
        }
}

// ---------------- per-point voxel index + histogram (wave-aggregated) --------
__global__ __launch_bounds__(256) void point_voxel_k(
    const double* __restrict__ gc, int* __restrict__ vidx, int* __restrict__ cnt)
{
    const int i = blockIdx.x * 256 + threadIdx.x;
    if (i >= NPTS) return;
    const int lane = threadIdx.x & 63;
    const int n = i / (DCH * SP_);
    int r = i - n * (DCH * SP_);
    const int di = r / SP_;
    const int s = r - di * SP_;
    const int h = s / FW_, w = s - h * FW_;
    const double* g = gc + n * 24;
    const double u  = (double)(float)((double)w * (703.0 / 43.0));
    const double v  = (double)(float)((double)h * 17.0);
    const double dd = (double)(float)(2.0 + (double)di * (56.0 / 111.0));
    const double rx = g[0] * u + g[1] * v + g[2] + g[9];
    const double ry = g[3] * u + g[4] * v + g[5] + g[10];
    const double rz = g[6] * u + g[7] * v + g[8] + g[11];
    const double px = rx * dd, py = ry * dd, pz = rz * dd;
    const double ex = g[12] * px + g[13] * py + g[14] * pz + g[15];
    const double ey = g[16] * px + g[17] * py + g[18] * pz + g[19];
    const double ez = g[20] * px + g[21] * py + g[22] * pz + g[23];
    const double vs_xy = 0.8, vs_z = 8.0;
    const double offx = (double)(float)(-51.2 + 0.4) - vs_xy * 0.5;
    const double offz = (double)(float)(-5.0 + 4.0) - vs_z * 0.5;
    const int gx = (int)((ex - offx) / vs_xy);
    const int gy = (int)((ey - offx) / vs_xy);
    const int gz = (int)((ez - offz) / vs_z);
    const bool ok = (gx >= 0 && gx < NXY && gy >= 0 && gy < NXY && gz == 0);
    const int vv = ok ? (gy * NXY + gx) : -1;
    vidx[i] = vv;
    unsigned long long unresolved = __ballot(vv >= 0);
    while (unresolved) {
        const int src = __ffsll(unresolved) - 1;
        const int v0 = __shfl(vv, src);
        const unsigned long long grp = __ballot(vv == v0);
        if (lane == src) atomicAdd(&cnt[v0], __popcll(grp));
        unresolved &= ~grp;
    }
}

// off has NVOX+1 entries; off[NVOX] = total valid points
__global__ void prefix_k(const int* __restrict__ cnt, int* __restrict__ off,
                         int* __restrict__ cur) {
    __shared__ int part[256];
    const int t = threadIdx.x;
    int s = 0;
    for (int j = 0; j < 64; ++j) s += cnt[t * 64 + j];
    part[t] = s;
    __syncthreads();
    if (t == 0) {
        int run = 0;
        for (int k = 0; k < 256; ++k) { int v = part[k]; part[k] = run; run += v; }
    }
    __syncthreads();
    int base = part[t];
    for (int j = 0; j < 64; ++j) {
        off[t * 64 + j] = base;
        cur[t * 64 + j] = base;
        base += cnt[t * 64 + j];
    }
    if (t == 255) off[NVOX] = base;
}

// fill packed entries: key = (v<<13) | (n*SP_+s), prob bits; prob [n][s][112]
__global__ __launch_bounds__(256) void fill_k(
    const int* __restrict__ vidx, const float* __restrict__ prob,
    int* __restrict__ cur, int2* __restrict__ pk) {
    int i = blockIdx.x * 256 + threadIdx.x;
    if (i >= NPTS) return;
    const int lane = threadIdx.x & 63;
    const int v = vidx[i];
    const int n = i / (DCH * SP_);
    int r = i - n * (DCH * SP_);
    const int di = r / SP_;
    const int s = r - di * SP_;
    float p = 0.f;
    if (v >= 0) p = prob[((size_t)n * SP_ + s) * DCH + di];

    int pos = -1;
    unsigned long long unresolved = __ballot(v >= 0);
    while (unresolved) {
        const int src = __ffsll(unresolved) - 1;
        const int v0 = __shfl(v, src);
        const unsigned long long grp = __ballot(v == v0);
        int base = 0;
        if (lane == src) base = atomicAdd(&cur[v0], __popcll(grp));
        base = __shfl(base, src);
        if (v == v0) {
            const int rank = __popcll(grp & ((1ull << lane) - 1ull));
            pos = base + rank;
        }
        unresolved &= ~grp;
    }
    if (v >= 0)
        pk[pos] = make_int2((v << 13) | (n * SP_ + s), __float_as_int(p));
}

// ---------------- gather: chunk-per-wave segmented reduction ------------------
__global__ __launch_bounds__(256) void gather2_k(
    const int2* __restrict__ pk, const int* __restrict__ off,
    const float* __restrict__ ctxT, float* __restrict__ accT)
{
    const int gtid = blockIdx.x * 256 + threadIdx.x;
    const int wid = gtid >> 6;
    const int lane = threadIdx.x & 63;
    const int total = off[NVOX];
    const int lo = wid * CHUNK;
    if (lo >= total) return;
    const int hi = min(lo + CHUNK, total);
    float a0 = 0.f, a1 = 0.f;
    int2 e = pk[lo];
    for (int k = lo; k < hi; ++k) {
        const int2 en = (k + 1 < hi) ? pk[k + 1] : make_int2(-1, 0);
        const float p = __int_as_float(e.y);
        const int ns = e.x & 8191;
        const float* cb = ctxT + (size_t)ns * CCTX;
        a0 = fmaf(p, cb[lane], a0);
        if (lane < CCTX - 64) a1 = fmaf(p, cb[64 + lane], a1);
        if ((en.x >> 13) != (e.x >> 13)) {         // wave-uniform flush
            float* ab = accT + (size_t)(e.x >> 13) * CCTX;
            atomicAdd(ab + lane, a0);
            if (lane < CCTX - 64) atomicAdd(ab + 64 + lane, a1);
            a0 = a1 = 0.f;
        }
        e = en;
    }
}

// ---------------- transpose accT [v][c] -> out [c][v] ------------------------
__global__ void transpose_out_k(const float* __restrict__ accT, float* __restrict__ out) {
    const int idx = blockIdx.x * 256 + threadIdx.x;
    if (idx >= CCTX * NVOX) return;
    const int c = idx >> 14;
    const int v = idx & 16383;
    out[idx] = accT[(size_t)v * CCTX + c];
}

// ---------------- workspace layout (float offsets) ---------------------------
#define O_WHIA  512           // bf16 conv weights W2-A [32][9][512][16]
#define O_WHIB  1180160       // fp16 partial chunks 0-5 (during conv)
#define O_XT0   2359808       // 1,474,560  (chunked [n][32][960][16])
#define O_XT1   3834368       // 1,474,560
#define O_XT2   5308928       // 1,474,560; doubles as W2-B buffer until d1 combine
#define O_WD2B  6783488       // fp16 partial chunks 6-23 during conv; then 1x1 wts
#define O_WC2B  6812160       // 20,480 (bf16 80x512)
#define O_DLG   6832640       // (unused since softmax fusion; kept for layout)
#define O_DPR   7305728       // 473,088  depth probs [n][s][112]
#define O_CTX   7778816       // 337,920  [n][s][80]
#define O_PK    8116736       // 946,176 (int2 x 473,088)
#define O_VIX   9062912       // 473,088
#define O_CNT   9536000       // 16,384   (ZBASE)
#define O_OFF   9552384       // 16,400
#define O_CUR   9568784       // 16,384
#define O_ACC   9585168       // 1,310,720
// end: 10,895,888 floats = 43.6 MB (unchanged)

extern "C" void kernel_launch(void* const* d_in, const int* in_sizes, int n_in,
                              void* d_out, int out_size, void* d_ws, size_t ws_size,
                              hipStream_t stream)
{
    const float* src  = (const float*)d_in[0];
    const float* w_s1 = (const float*)d_in[1];
    const float* w_s2 = (const float*)d_in[2];
    const float* w_d1 = (const float*)d_in[3];
    const float* w_d2 = (const float*)d_in[4];
    const float* b_d  = (const float*)d_in[5];
    const float* w_c1 = (const float*)d_in[6];
    const float* w_c2 = (const float*)d_in[7];
    const float* b_c  = (const float*)d_in[8];
    const float* s2e  = (const float*)d_in[9];
    const float* intr = (const float*)d_in[10];
    const float* ida  = (const float*)d_in[11];
    const float* bda  = (const float*)d_in[12];

    double* gc = (double*)d_ws;
    float* ws   = (float*)d_ws;
    short* whiA = (short*)(ws + O_WHIA);
    short* whiC = (short*)(ws + O_XT2);          // W2-B buffer (dead xt2 region)
    _Float16* pA = (_Float16*)(ws + O_WHIB);     // chunks 0-5
    _Float16* pB = (_Float16*)(ws + O_WD2B);     // chunks 6-23
    short* xt0  = (short*)(ws + O_XT0);
    short* xt1  = (short*)(ws + O_XT1);
    short* xt2  = (short*)(ws + O_XT2);
    short* wd2b = (short*)(ws + O_WD2B);
    short* wc2b = (short*)(ws + O_WC2B);
    float* dprb = ws + O_DPR;
    float* ctxT = ws + O_CTX;
    int2*  pk   = (int2*)(ws + O_PK);
    int* vidx   = (int*)(ws + O_VIX);
    int* cnt    = (int*)(ws + O_CNT);
    int* offs   = (int*)(ws + O_OFF);
    int* cur    = (int*)(ws + O_CUR);
    float* accT = ws + O_ACC;
    float* out  = (float*)d_out;

    const int CMB = (NIMG * SP_ * CIN / 4 + 255) / 256;   // 2112 blocks

    // zero xt0+xt1 (contiguous; provides pad borders). xt2 rows fully written
    // by d1-combine before being read -> no zeroing needed.
    zero_k<<<(2949120 / 4 + 255) / 256, 256, 0, stream>>>((float4*)xt0, 2949120 / 4);

    geom_setup_k<<<1, 64, 0, stream>>>(s2e, intr, ida, bda, gc);
    src_to_xt_k<<<(NIMG * SP_ * CIN + 255) / 256, 256, 0, stream>>>(src, xt0);

    // s1+s2 weight convert (dual); s1: xt0 -> xt1; s2: xt1 -> xt0
    wsplit2_k<<<(2 * CIN * CIN) / 256, 256, 0, stream>>>(w_s1, whiA, w_s2, whiC);
    conv6_k<<<576, 256, 0, stream>>>(xt0, whiA, pA, pB);
    combine6_k<<<CMB, 256, 0, stream>>>(pA, pB, xt1);
    conv6_k<<<576, 256, 0, stream>>>(xt1, whiC, pA, pB);
    combine6_k<<<CMB, 256, 0, stream>>>(pA, pB, xt0);
    // c1+d1 weight convert (dual), then FUSED dual conv (K-split x2/layer)
    wsplit2_k<<<(2 * CIN * CIN) / 256, 256, 0, stream>>>(w_c1, whiA, w_d1, whiC);
    conv6d_k<<<576, 256, 0, stream>>>(xt0, whiA, whiC, pA, pB);
    combine6d_k<<<2 * CMB, 256, 0, stream>>>(pA, pB, xt1, xt2);  // xt2 overwrites whiC (done)

    // postprep: 1x1 weights (both) + zero cnt/off/cur/accT -- AFTER convs
    {
        const int NW = (DCH + CCTX) * CIN;           // 98,304
        const int blocks = (NW + ZLEN4 + 255) / 256; // 1,713
        postprep_k<<<blocks, 256, 0, stream>>>(w_d2, wd2b, w_c2, wc2b,
                                               (float4*)(ws + ZBASE));
    }
    // merged d2 + c2 gemms with fused depth softmax:
    // xt2 -> dprb [n][s][112] (probs), xt1 -> ctxT [n][s][80]
    gemm1x1d_k<<<dim3(11, 2, NIMG), 256, 0, stream>>>(xt2, wd2b, b_d, dprb,
                                                      xt1, wc2b, b_c, ctxT);

    // binning
    point_voxel_k<<<(NPTS + 255) / 256, 256, 0, stream>>>(gc, vidx, cnt);
    prefix_k<<<1, 256, 0, stream>>>(cnt, offs, cur);
    fill_k<<<(NPTS + 255) / 256, 256, 0, stream>>>(vidx, dprb, cur, pk);

    // segmented-reduction gather (accT zeroed by postprep)
    {
        const int waves = (NPTS + CHUNK - 1) / CHUNK;
        const int blocks = (waves + 3) / 4;
        gather2_k<<<blocks, 256, 0, stream>>>(pk, offs, ctxT, accT);
    }
    transpose_out_k<<<(CCTX * NVOX + 255) / 256, 256, 0, stream>>>(accT, out);

    (void)in_sizes; (void)n_in; (void)out_size; (void)ws_size;
}

// Round 11
// 366.843 us; speedup vs baseline: 1.0179x; 1.0179x over previous
//
#include <hip/hip_runtime.h>

// LSS-FPN round 21: swizzle reverted (R20 null -> conv6/conv6d frozen at
// R19-proven form). combine6d ELIMINATED: gemm1x1f_k reads the two fp16
// partial chunks per head directly ([s][512] layout), add+relu+bf16 inline.
// Relocations (chunk liveness): dprb/ctxT/1x1-weights -> dead xt1 region;
// cnt/accT zeroing moved to after the gemm (chunks 21-23 overlap it).

#define FH_ 16
#define FW_ 44
#define SP_ 704
#define XSTR 960         // xt rows per image (incl. halo slack)
#define NIMG 6
#define CIN 512
#define DCH 112
#define CCTX 80
#define NXY 128
#define NVOX (NXY * NXY)
#define NPTS (NIMG * DCH * SP_)
#define CHUNK 64

#define NKC6 8           // kc steps for K-split x4 conv (16 ci each)
#define HCHK 360448      // fp16 partial chunk: 704*512 halves
#define CIP 40           // padded LDS k-stride for gemm1x1 (shorts)

typedef unsigned short u16;
typedef unsigned int u32;
typedef __attribute__((ext_vector_type(8))) short bf16x8;
typedef __attribute__((ext_vector_type(4))) short s16x4;
typedef __attribute__((ext_vector_type(8))) _Float16 h8;
typedef __attribute__((ext_vector_type(4))) float f32x4;
typedef __attribute__((ext_vector_type(16))) float f32x16;

__device__ __forceinline__ float bf2f(u16 b) {
    union { unsigned u; float f; } v; v.u = ((unsigned)b) << 16; return v.f;
}
__device__ __forceinline__ u16 f2bf(float f) {
    union { float f; unsigned u; } v; v.f = f;
    unsigned r = v.u + 0x7fffu + ((v.u >> 16) & 1u);   // RTNE
    return (u16)(r >> 16);
}
__device__ __forceinline__ int spad_of(int s) {
    return (s / 44) * 46 + (s % 44) + 47;
}
__device__ __forceinline__ void gld_lds16(const void* gsrc, void* ldst) {
    __builtin_amdgcn_global_load_lds(
        (const __attribute__((address_space(1))) u32*)gsrc,
        (__attribute__((address_space(3))) u32*)ldst, 16, 0, 0);
}
// fp16 partial chunk c in [0,24): chunks 0-5 in dead whiB region (pA),
// chunks 6-23 in post-conv tail region (pB).
__device__ __forceinline__ const _Float16* chunkc(const _Float16* pA,
                                                  const _Float16* pB, int c) {
    return (c < 6) ? (pA + (size_t)c * HCHK) : (pB + (size_t)(c - 6) * HCHK);
}
__device__ __forceinline__ _Float16* chunkw(_Float16* pA, _Float16* pB, int c) {
    return (c < 6) ? (pA + (size_t)c * HCHK) : (pB + (size_t)(c - 6) * HCHK);
}

// ---------------- zero fill ---------------------------------------------------
__global__ void zero_k(float4* __restrict__ p, long n4) {
    long i = (long)blockIdx.x * blockDim.x + threadIdx.x;
    if (i < n4) p[i] = make_float4(0.f, 0.f, 0.f, 0.f);
}

// ------- src fp32 [n][ci][704] -> xt2 bf16 chunked [n][32][960][16] ----------
__global__ void src_to_xt_k(const float* __restrict__ src, short* __restrict__ xt) {
    int e = blockIdx.x * 256 + threadIdx.x;
    if (e >= NIMG * SP_ * CIN) return;
    int ci = e & 511;
    int r = e >> 9;
    int s = r % SP_, n = r / SP_;
    float v = src[((size_t)n * CIN + ci) * SP_ + s];
    xt[(((size_t)n * 32 + (ci >> 4)) * XSTR + spad_of(s)) * 16 + (ci & 15)] = (short)f2bf(v);
}

// ------- weight convert: fp32 [co][ci][9] -> W2 bf16 [kc][t][co][16] ---------
// dual: two tensors in one dispatch (grid 2 * CIN*CIN / 256)
__global__ void wsplit2_k(const float* __restrict__ wA, short* __restrict__ oA,
                          const float* __restrict__ wB, short* __restrict__ oB) {
    int i = blockIdx.x * 256 + threadIdx.x;
    if (i >= 2 * CIN * CIN) return;
    const int e = i & (CIN * CIN - 1);
    const float* __restrict__ w = (i < CIN * CIN) ? wA : wB;
    short* __restrict__ o = (i < CIN * CIN) ? oA : oB;
    const int co = e >> 9, ci = e & 511;
    const float* wp = w + (size_t)e * 9;
#pragma unroll
    for (int t = 0; t < 9; ++t)
        o[((((size_t)(ci >> 4) * 9) + t) * CIN + co) * 16 + (ci & 15)] = (short)f2bf(wp[t]);
}

// dual 1x1 weights fp32 [co][ci] -> bf16 (flat [co][ci])
__global__ void wsplit1_dual_k(const float* __restrict__ wd, short* __restrict__ od,
                               const float* __restrict__ wc, short* __restrict__ oc) {
    int i = blockIdx.x * 256 + threadIdx.x;
    if (i < DCH * CIN) od[i] = (short)f2bf(wd[i]);
    else if (i < DCH * CIN + CCTX * CIN) {
        int j = i - DCH * CIN;
        oc[j] = (short)f2bf(wc[j]);
    }
}

// ---------------- conv3x3, K-split x4, global_load_lds staging (R15) ---------
// grid 576: bid = (n*6+sb)*16 + (cb*4+q). Block: 128sp x 128co x 128ci.
// 4 waves (mw,nw) each 64sp x 64co (M2N2). fp16 partial out [s][512co].
__global__ __launch_bounds__(256, 3) void conv6_k(
    const short* __restrict__ xt2, const short* __restrict__ w2,
    _Float16* __restrict__ pA, _Float16* __restrict__ pB)
{
    __shared__ short Xs[256 * 16];        // 8,192 B (232 rows used + slack)
    __shared__ short Wsh[1152 * 16];      // 36,864 B
    const int tid = threadIdx.x;
    const int lane = tid & 63, wave = tid >> 6;
    const int l31 = lane & 31, lh = lane >> 5;
    const int mw = wave >> 1, nw = wave & 1;

    const int bid = blockIdx.x;
    const int c16 = bid & 15;
    const int cb = c16 >> 2, q = c16 & 3;
    const int rest = bid >> 4;
    const int n = rest / 6, sb = rest - (rest / 6) * 6;

    const int s0 = sb * 128;
    const int co0 = cb * 128;
    const int base = spad_of(s0) - 47;

    const short* __restrict__ xq = xt2 + (((size_t)n * 32 + q * 8) * XSTR + base) * 16;
    const short* __restrict__ wq = w2 + (((size_t)(q * 8) * 9) * CIN + co0) * 16;

    int sloc[2];
#pragma unroll
    for (int mf = 0; mf < 2; ++mf)
        sloc[mf] = spad_of(s0 + mw * 64 + mf * 32 + l31) - base;

    const f32x16 z16 = {0.f,0.f,0.f,0.f,0.f,0.f,0.f,0.f,
                        0.f,0.f,0.f,0.f,0.f,0.f,0.f,0.f};
    f32x16 acc[2][2];
    acc[0][0] = z16; acc[0][1] = z16; acc[1][0] = z16; acc[1][1] = z16;

#define STAGE6(KC) do {                                                         \
    const short* xc = xq + (size_t)(KC) * (XSTR * 16) + lane * 8;               \
    const short* wc = wq + (size_t)(KC) * (9 * CIN * 16) + lane * 8;            \
    _Pragma("unroll")                                                           \
    for (int i = 0; i < 11; ++i) {                                              \
        const int sg = wave + 4 * i;                                            \
        if (sg < 8) {                                                           \
            gld_lds16(xc + sg * 512, &Xs[sg * 512]);                            \
        } else {                                                                \
            const int j = sg - 8, t = j >> 2, s4 = j & 3;                       \
            gld_lds16(wc + t * (CIN * 16) + s4 * 512, &Wsh[sg * 512 - 4096]);   \
        }                                                                       \
    }                                                                           \
} while (0)

    STAGE6(0);
    __syncthreads();

    constexpr int OFF[9] = {-47, -46, -45, -1, 0, 1, 45, 46, 47};
    for (int kc = 0; kc < NKC6; ++kc) {
#pragma unroll
        for (int t9 = 0; t9 < 9; ++t9) {
            const int off = OFF[t9];
            bf16x8 a0 = *(const bf16x8*)&Xs[(sloc[0] + off) * 16 + lh * 8];
            bf16x8 a1 = *(const bf16x8*)&Xs[(sloc[1] + off) * 16 + lh * 8];
            bf16x8 b0 = *(const bf16x8*)&Wsh[(t9 * 128 + nw * 64 + l31) * 16 + lh * 8];
            bf16x8 b1 = *(const bf16x8*)&Wsh[(t9 * 128 + nw * 64 + 32 + l31) * 16 + lh * 8];
            acc[0][0] = __builtin_amdgcn_mfma_f32_32x32x16_bf16(a0, b0, acc[0][0], 0, 0, 0);
            acc[0][1] = __builtin_amdgcn_mfma_f32_32x32x16_bf16(a0, b1, acc[0][1], 0, 0, 0);
            acc[1][0] = __builtin_amdgcn_mfma_f32_32x32x16_bf16(a1, b0, acc[1][0], 0, 0, 0);
            acc[1][1] = __builtin_amdgcn_mfma_f32_32x32x16_bf16(a1, b1, acc[1][1], 0, 0, 0);
        }
        __syncthreads();
        if (kc + 1 < NKC6) {
            STAGE6(kc + 1);
            __syncthreads();
        }
    }
#undef STAGE6

    _Float16* __restrict__ Pc = chunkw(pA, pB, q * 6 + n);
#pragma unroll
    for (int mf = 0; mf < 2; ++mf) {
        const int spb = mw * 64 + mf * 32 + 4 * lh;
#pragma unroll
        for (int r = 0; r < 16; ++r) {
            const int sg = s0 + spb + (r & 3) + 8 * (r >> 2);
            if (sg < SP_) {
                const size_t ro = (size_t)sg * 512 + co0 + nw * 64 + l31;
                Pc[ro] = (_Float16)acc[mf][0][r];
                Pc[ro + 32] = (_Float16)acc[mf][1][r];
            }
        }
    }
}

// ---------------- dual conv (c1+d1), K-split x2 per layer --------------------
// grid 576: bid = (n*6+sb)*16 + (cb*4 + layer*2 + q); q in [0,2) selects
// 256-ci half; NKC=16. Partial chunk c = layer*12 + q*6 + n (24 chunks).
__global__ __launch_bounds__(256, 3) void conv6d_k(
    const short* __restrict__ xt2, const short* __restrict__ wA,
    const short* __restrict__ wB,
    _Float16* __restrict__ pA, _Float16* __restrict__ pB)
{
    __shared__ short Xs[256 * 16];
    __shared__ short Wsh[1152 * 16];
    const int tid = threadIdx.x;
    const int lane = tid & 63, wave = tid >> 6;
    const int l31 = lane & 31, lh = lane >> 5;
    const int mw = wave >> 1, nw = wave & 1;

    const int bid = blockIdx.x;
    const int c16 = bid & 15;
    const int cb = c16 >> 2;
    const int layer = (c16 >> 1) & 1, q = c16 & 1;
    const int rest = bid >> 4;
    const int n = rest / 6, sb = rest - (rest / 6) * 6;

    const int s0 = sb * 128;
    const int co0 = cb * 128;
    const int base = spad_of(s0) - 47;

    const short* __restrict__ w2 = layer ? wB : wA;
    const short* __restrict__ xq = xt2 + (((size_t)n * 32 + q * 16) * XSTR + base) * 16;
    const short* __restrict__ wq = w2 + (((size_t)(q * 16) * 9) * CIN + co0) * 16;

    int sloc[2];
#pragma unroll
    for (int mf = 0; mf < 2; ++mf)
        sloc[mf] = spad_of(s0 + mw * 64 + mf * 32 + l31) - base;

    const f32x16 z16 = {0.f,0.f,0.f,0.f,0.f,0.f,0.f,0.f,
                        0.f,0.f,0.f,0.f,0.f,0.f,0.f,0.f};
    f32x16 acc[2][2];
    acc[0][0] = z16; acc[0][1] = z16; acc[1][0] = z16; acc[1][1] = z16;

#define STAGE6D(KC) do {                                                        \
    const short* xc = xq + (size_t)(KC) * (XSTR * 16) + lane * 8;               \
    const short* wc = wq + (size_t)(KC) * (9 * CIN * 16) + lane * 8;            \
    _Pragma("unroll")                                                           \
    for (int i = 0; i < 11; ++i) {                                              \
        const int sg = wave + 4 * i;                                            \
        if (sg < 8) {                                                           \
            gld_lds16(xc + sg * 512, &Xs[sg * 512]);                            \
        } else {                                                                \
            const int j = sg - 8, t = j >> 2, s4 = j & 3;                       \
            gld_lds16(wc + t * (CIN * 16) + s4 * 512, &Wsh[sg * 512 - 4096]);   \
        }                                                                       \
    }                                                                           \
} while (0)

    STAGE6D(0);
    __syncthreads();

    constexpr int OFF[9] = {-47, -46, -45, -1, 0, 1, 45, 46, 47};
    for (int kc = 0; kc < 16; ++kc) {
#pragma unroll
        for (int t9 = 0; t9 < 9; ++t9) {
            const int off = OFF[t9];
            bf16x8 a0 = *(const bf16x8*)&Xs[(sloc[0] + off) * 16 + lh * 8];
            bf16x8 a1 = *(const bf16x8*)&Xs[(sloc[1] + off) * 16 + lh * 8];
            bf16x8 b0 = *(const bf16x8*)&Wsh[(t9 * 128 + nw * 64 + l31) * 16 + lh * 8];
            bf16x8 b1 = *(const bf16x8*)&Wsh[(t9 * 128 + nw * 64 + 32 + l31) * 16 + lh * 8];
            acc[0][0] = __builtin_amdgcn_mfma_f32_32x32x16_bf16(a0, b0, acc[0][0], 0, 0, 0);
            acc[0][1] = __builtin_amdgcn_mfma_f32_32x32x16_bf16(a0, b1, acc[0][1], 0, 0, 0);
            acc[1][0] = __builtin_amdgcn_mfma_f32_32x32x16_bf16(a1, b0, acc[1][0], 0, 0, 0);
            acc[1][1] = __builtin_amdgcn_mfma_f32_32x32x16_bf16(a1, b1, acc[1][1], 0, 0, 0);
        }
        __syncthreads();
        if (kc + 1 < 16) {
            STAGE6D(kc + 1);
            __syncthreads();
        }
    }
#undef STAGE6D

    _Float16* __restrict__ Pc = chunkw(pA, pB, layer * 12 + q * 6 + n);
#pragma unroll
    for (int mf = 0; mf < 2; ++mf) {
        const int spb = mw * 64 + mf * 32 + 4 * lh;
#pragma unroll
        for (int r = 0; r < 16; ++r) {
            const int sg = s0 + spb + (r & 3) + 8 * (r >> 2);
            if (sg < SP_) {
                const size_t ro = (size_t)sg * 512 + co0 + nw * 64 + l31;
                Pc[ro] = (_Float16)acc[mf][0][r];
                Pc[ro + 32] = (_Float16)acc[mf][1][r];
            }
        }
    }
}

// ---------------- combine: relu(sum of 4 chunks) -> bf16 chunked xt ----------
__global__ __launch_bounds__(256) void combine6_k(
    const _Float16* __restrict__ pA, const _Float16* __restrict__ pB,
    short* __restrict__ xout)
{
    const int i = blockIdx.x * 256 + threadIdx.x;
    if (i >= NIMG * SP_ * CIN / 4) return;
    const int e = i * 4;
    const int n = e / (SP_ * CIN);
    const int r = e - n * (SP_ * CIN);
    const int s = r >> 9, co = r & 511;
    union h4 { s16x4 s; _Float16 h[4]; };
    float v[4] = {0.f, 0.f, 0.f, 0.f};
#pragma unroll
    for (int q = 0; q < 4; ++q) {
        const _Float16* c = chunkc(pA, pB, q * 6 + n);
        h4 u; u.s = *(const s16x4*)(c + r);
#pragma unroll
        for (int j = 0; j < 4; ++j) v[j] += (float)u.h[j];
    }
    s16x4 o;
#pragma unroll
    for (int j = 0; j < 4; ++j) o[j] = (short)f2bf(fmaxf(v[j], 0.f));
    *(s16x4*)&xout[(((size_t)n * 32 + (co >> 4)) * XSTR + spad_of(s)) * 16 + (co & 15)] = o;
}

// ------- merged 1x1 convs (d2+c2) reading fp16 partials directly -------------
// grid (11, 2, 6): y=0 -> depth head (layer1 chunks, softmax, writes probs),
//                  y=1 -> context head (layer0 chunks, bias only).
// A built inline: add 2 fp16 partial chunks, relu, RTNE bf16 (== combine6d).
__global__ __launch_bounds__(256, 2) void gemm1x1f_k(
    const _Float16* __restrict__ pA, const _Float16* __restrict__ pB,
    const short* __restrict__ wD, const float* __restrict__ bD, float* __restrict__ oD,
    const short* __restrict__ wC, const float* __restrict__ bC, float* __restrict__ oC)
{
    const int sel = blockIdx.y;
    const int L = sel ? 0 : 1;                    // depth=layer1, context=layer0
    const short* __restrict__ wb   = sel ? wC : wD;
    const float* __restrict__ bias = sel ? bC : bD;
    float* __restrict__ outT       = sel ? oC : oD;
    const int nst = sel ? (CCTX / 16) : (DCH / 16);   // 5 or 7
    const int nco = nst * 16;

    __shared__ short Wb[DCH * CIP];
    const int tid = threadIdx.x;
    const int s0 = blockIdx.x * 64, n = blockIdx.z;
    const int lane = tid & 63, wave = tid >> 6;
    const int kg = lane >> 4, lrow = lane & 15;
    const int swave = s0 + wave * 16;
    const int arow = swave + lrow;                // plain [s][512] partial layout

    const _Float16* __restrict__ c0 = chunkc(pA, pB, L * 12 + n);
    const _Float16* __restrict__ c1 = chunkc(pA, pB, L * 12 + 6 + n);

    const f32x4 zero4 = {0.f, 0.f, 0.f, 0.f};
    f32x4 acc[7];
#pragma unroll
    for (int ns = 0; ns < 7; ++ns) acc[ns] = zero4;

    for (int kc = 0; kc < 16; ++kc) {
        __syncthreads();
#pragma unroll
        for (int it = 0; it < 2; ++it) {
            int q = it * 256 + tid;
            if (q < nco * 4) {
                int co = q >> 2, p = q & 3;
                *(bf16x8*)&Wb[co * CIP + p * 8] =
                    *(const bf16x8*)(wb + (size_t)co * CIN + kc * 32 + p * 8);
            }
        }
        __syncthreads();
        const size_t ao = (size_t)arow * 512 + kc * 32 + kg * 8;
        h8 u0 = *(const h8*)(c0 + ao);
        h8 u1 = *(const h8*)(c1 + ao);
        bf16x8 a;
#pragma unroll
        for (int j = 0; j < 8; ++j) {
            float f = fmaxf((float)u0[j] + (float)u1[j], 0.f);
            a[j] = (short)f2bf(f);
        }
#pragma unroll
        for (int ns = 0; ns < 7; ++ns) {
            if (ns < nst) {
                int co = ns * 16 + lrow;
                bf16x8 b = *(const bf16x8*)&Wb[co * CIP + kg * 8];
                acc[ns] = __builtin_amdgcn_mfma_f32_16x16x32_bf16(a, b, acc[ns], 0, 0, 0);
            }
        }
    }
    // bias
#pragma unroll
    for (int ns = 0; ns < 7; ++ns) {
        if (ns < nst) {
            const float bv = bias[ns * 16 + lrow];
#pragma unroll
            for (int r = 0; r < 4; ++r) acc[ns][r] += bv;
        }
    }
    // fused softmax for the depth head (exactly 112 channels in 7 regs x 16 lanes)
    if (sel == 0) {
#pragma unroll
        for (int r = 0; r < 4; ++r) {
            float m = acc[0][r];
#pragma unroll
            for (int ns = 1; ns < 7; ++ns) m = fmaxf(m, acc[ns][r]);
#pragma unroll
            for (int o = 8; o; o >>= 1) m = fmaxf(m, __shfl_xor(m, o));
            float ssum = 0.f;
#pragma unroll
            for (int ns = 0; ns < 7; ++ns) {
                float ev = __expf(acc[ns][r] - m);
                acc[ns][r] = ev; ssum += ev;
            }
#pragma unroll
            for (int o = 8; o; o >>= 1) ssum += __shfl_xor(ssum, o);
            const float inv = 1.f / ssum;
#pragma unroll
            for (int ns = 0; ns < 7; ++ns) acc[ns][r] *= inv;
        }
    }
#pragma unroll
    for (int ns = 0; ns < 7; ++ns) {
        if (ns < nst) {
#pragma unroll
            for (int r = 0; r < 4; ++r) {
                const int sg = swave + kg * 4 + r;
                const int co = ns * 16 + lrow;
                outT[((size_t)n * SP_ + sg) * nco + co] = acc[ns][r];
            }
        }
    }
}

// ---------------- per-camera geometry constants (fp64, closed-form) ----------
__device__ __forceinline__ void inv4(const double* M, double* inv) {
    inv[0]  =  M[5]*M[10]*M[15] - M[5]*M[11]*M[14] - M[9]*M[6]*M[15] + M[9]*M[7]*M[14] + M[13]*M[6]*M[11] - M[13]*M[7]*M[10];
    inv[4]  = -M[4]*M[10]*M[15] + M[4]*M[11]*M[14] + M[8]*M[6]*M[15] - M[8]*M[7]*M[14] - M[12]*M[6]*M[11] + M[12]*M[7]*M[10];
    inv[8]  =  M[4]*M[9]*M[15]  - M[4]*M[11]*M[13] - M[8]*M[5]*M[15] + M[8]*M[7]*M[13] + M[12]*M[5]*M[11] - M[12]*M[7]*M[9];
    inv[12] = -M[4]*M[9]*M[14]  + M[4]*M[10]*M[13] + M[8]*M[5]*M[14] - M[8]*M[6]*M[13] - M[12]*M[5]*M[10] + M[12]*M[6]*M[9];
    inv[1]  = -M[1]*M[10]*M[15] + M[1]*M[11]*M[14] + M[9]*M[2]*M[15] - M[9]*M[3]*M[14] - M[13]*M[2]*M[11] + M[13]*M[3]*M[10];
    inv[5]  =  M[0]*M[10]*M[15] - M[0]*M[11]*M[14] - M[8]*M[2]*M[15] + M[8]*M[3]*M[14] + M[12]*M[2]*M[11] - M[12]*M[3]*M[10];
    inv[9]  = -M[0]*M[9]*M[15]  + M[0]*M[11]*M[13] + M[8]*M[1]*M[15] - M[8]*M[3]*M[13] - M[12]*M[1]*M[11] + M[12]*M[3]*M[9];
    inv[13] =  M[0]*M[9]*M[14]  - M[0]*M[10]*M[13] - M[8]*M[1]*M[14] + M[8]*M[2]*M[13] + M[12]*M[1]*M[10] - M[12]*M[2]*M[9];
    inv[2]  =  M[1]*M[6]*M[15]  - M[1]*M[7]*M[14]  - M[5]*M[2]*M[15] + M[5]*M[3]*M[14] + M[13]*M[2]*M[7]  - M[13]*M[3]*M[6];
    inv[6]  = -M[0]*M[6]*M[15]  + M[0]*M[7]*M[14]  + M[4]*M[2]*M[15] - M[4]*M[3]*M[14] - M[12]*M[2]*M[7]  + M[12]*M[3]*M[6];
    inv[10] =  M[0]*M[5]*M[15]  - M[0]*M[7]*M[13]  - M[4]*M[1]*M[15] + M[4]*M[3]*M[13] + M[12]*M[1]*M[7]  - M[12]*M[3]*M[5];
    inv[14] = -M[0]*M[5]*M[14]  + M[0]*M[6]*M[13]  + M[4]*M[1]*M[14] - M[4]*M[2]*M[13] - M[12]*M[1]*M[6]  + M[12]*M[2]*M[5];
    inv[3]  = -M[1]*M[6]*M[11]  + M[1]*M[7]*M[10]  + M[5]*M[2]*M[11] - M[5]*M[3]*M[10] - M[9]*M[2]*M[7]   + M[9]*M[3]*M[6];
    inv[7]  =  M[0]*M[6]*M[11]  - M[0]*M[7]*M[10]  - M[4]*M[2]*M[11] + M[4]*M[3]*M[10] + M[8]*M[2]*M[7]   - M[8]*M[3]*M[6];
    inv[11] = -M[0]*M[5]*M[11]  + M[0]*M[7]*M[9]   + M[4]*M[1]*M[11] - M[4]*M[3]*M[9]  - M[8]*M[1]*M[7]   + M[8]*M[3]*M[5];
    inv[15] =  M[0]*M[5]*M[10]  - M[0]*M[6]*M[9]   - M[4]*M[1]*M[10] + M[4]*M[2]*M[9]  + M[8]*M[1]*M[6]   - M[8]*M[2]*M[5];
    double det = M[0]*inv[0] + M[1]*inv[4] + M[2]*inv[8] + M[3]*inv[12];
    double id = 1.0 / det;
#pragma unroll
    for (int i = 0; i < 16; ++i) inv[i] *= id;
}

__global__ void geom_setup_k(const float* __restrict__ s2e, const float* __restrict__ intrin,
                             const float* __restrict__ ida, const float* __restrict__ bda,
                             double* __restrict__ gc)
{
    const int n = threadIdx.x;
    if (n >= NIMG) return;
    double M[16], Iv[16];
#pragma unroll
    for (int i = 0; i < 16; ++i) M[i] = (double)ida[n * 16 + i];
    inv4(M, Iv);
    double R[3][3], tv[3];
#pragma unroll
    for (int r = 0; r < 3; ++r) {
#pragma unroll
        for (int c = 0; c < 3; ++c) R[r][c] = Iv[r * 4 + c];
        tv[r] = Iv[r * 4 + 3];
    }
    double K[3][3];
#pragma unroll
    for (int r = 0; r < 3; ++r)
#pragma unroll
        for (int c = 0; c < 3; ++c) K[r][c] = (double)intrin[n * 16 + r * 4 + c];
    double det = K[0][0] * (K[1][1] * K[2][2] - K[1][2] * K[2][1])
               - K[0][1] * (K[1][0] * K[2][2] - K[1][2] * K[2][0])
               + K[0][2] * (K[1][0] * K[2][1] - K[1][1] * K[2][0]);
    double id = 1.0 / det;
    double Ki[3][3];
    Ki[0][0] = (K[1][1] * K[2][2] - K[1][2] * K[2][1]) * id;
    Ki[0][1] = (K[0][2] * K[2][1] - K[0][1] * K[2][2]) * id;
    Ki[0][2] = (K[0][1] * K[1][2] - K[0][2] * K[1][1]) * id;
    Ki[1][0] = (K[1][2] * K[2][0] - K[1][0] * K[2][2]) * id;
    Ki[1][1] = (K[0][0] * K[2][2] - K[0][2] * K[2][0]) * id;
    Ki[1][2] = (K[0][2] * K[1][0] - K[0][0] * K[1][2]) * id;
    Ki[2][0] = (K[1][0] * K[2][1] - K[1][1] * K[2][0]) * id;
    Ki[2][1] = (K[0][1] * K[2][0] - K[0][0] * K[2][1]) * id;
    Ki[2][2] = (K[0][0] * K[1][1] - K[0][1] * K[1][0]) * id;
    double A[3][3], bv[3];
#pragma unroll
    for (int r = 0; r < 3; ++r) {
#pragma unroll
        for (int c = 0; c < 3; ++c)
            A[r][c] = Ki[r][0] * R[0][c] + Ki[r][1] * R[1][c] + Ki[r][2] * R[2][c];
        bv[r] = Ki[r][0] * tv[0] + Ki[r][1] * tv[1] + Ki[r][2] * tv[2];
    }
    double* g = gc + n * 24;
#pragma unroll
    for (int r = 0; r < 3; ++r)
#pragma unroll
        for (int c = 0; c < 3; ++c) g[r * 3 + c] = A[r][c];
#pragma unroll
    for (int r = 0; r < 3; ++r) g[9 + r] = bv[r];
#pragma unroll
    for (int r = 0; r < 3; ++r)
#pragma unroll
        for (int c = 0; c < 4; ++c) {
            double acc = 0.0;
#pragma unroll
            for (int k = 0; k < 4; ++k)
                acc += (double)bda[r * 4 + k] * (double)s2e[n * 16 + k * 4 + c];
            g[12 + r * 4 + c] = acc;
        }
}

// ---------------- per-point voxel index + histogram (wave-aggregated) --------
__global__ __launch_bounds__(256) void point_voxel_k(
    const double* __restrict__ gc, int* __restrict__ vidx, int* __restrict__ cnt)
{
    const int i = blockIdx.x * 256 + threadIdx.x;
    if (i >= NPTS) return;
    const int lane = threadIdx.x & 63;
    const int n = i / (DCH * SP_);
    int r = i - n * (DCH * SP_);
    const int di = r / SP_;
    const int s = r - di * SP_;
    const int h = s / FW_, w = s - h * FW_;
    const double* g = gc + n * 24;
    const double u  = (double)(float)((double)w * (703.0 / 43.0));
    const double v  = (double)(float)((double)h * 17.0);
    const double dd = (double)(float)(2.0 + (double)di * (56.0 / 111.0));
    const double rx = g[0] * u + g[1] * v + g[2] + g[9];
    const double ry = g[3] * u + g[4] * v + g[5] + g[10];
    const double rz = g[6] * u + g[7] * v + g[8] + g[11];
    const double px = rx * dd, py = ry * dd, pz = rz * dd;
    const double ex = g[12] * px + g[13] * py + g[14] * pz + g[15];
    const double ey = g[16] * px + g[17] * py + g[18] * pz + g[19];
    const double ez = g[20] * px + g[21] * py + g[22] * pz + g[23];
    const double vs_xy = 0.8, vs_z = 8.0;
    const double offx = (double)(float)(-51.2 + 0.4) - vs_xy * 0.5;
    const double offz = (double)(float)(-5.0 + 4.0) - vs_z * 0.5;
    const int gx = (int)((ex - offx) / vs_xy);
    const int gy = (int)((ey - offx) / vs_xy);
    const int gz = (int)((ez - offz) / vs_z);
    const bool ok = (gx >= 0 && gx < NXY && gy >= 0 && gy < NXY && gz == 0);
    const int vv = ok ? (gy * NXY + gx) : -1;
    vidx[i] = vv;
    unsigned long long unresolved = __ballot(vv >= 0);
    while (unresolved) {
        const int src = __ffsll(unresolved) - 1;
        const int v0 = __shfl(vv, src);
        const unsigned long long grp = __ballot(vv == v0);
        if (lane == src) atomicAdd(&cnt[v0], __popcll(grp));
        unresolved &= ~grp;
    }
}

// off has NVOX+1 entries; off[NVOX] = total valid points
__global__ void prefix_k(const int* __restrict__ cnt, int* __restrict__ off,
                         int* __restrict__ cur) {
    __shared__ int part[256];
    const int t = threadIdx.x;
    int s = 0;
    for (int j = 0; j < 64; ++j) s += cnt[t * 64 + j];
    part[t] = s;
    __syncthreads();
    if (t == 0) {
        int run = 0;
        for (int k = 0; k < 256; ++k) { int v = part[k]; part[k] = run; run += v; }
    }
    __syncthreads();
    int base = part[t];
    for (int j = 0; j < 64; ++j) {
        off[t * 64 + j] = base;
        cur[t * 64 + j] = base;
        base += cnt[t * 64 + j];
    }
    if (t == 255) off[NVOX] = base;
}

// fill packed entries: key = (v<<13) | (n*SP_+s), prob bits; prob [n][s][112]
__global__ __launch_bounds__(256) void fill_k(
    const int* __restrict__ vidx, const float* __restrict__ prob,
    int* __restrict__ cur, int2* __restrict__ pk) {
    int i = blockIdx.x * 256 + threadIdx.x;
    if (i >= NPTS) return;
    const int lane = threadIdx.x & 63;
    const int v = vidx[i];
    const int n = i / (DCH * SP_);
    int r = i - n * (DCH * SP_);
    const int di = r / SP_;
    const int s = r - di * SP_;
    float p = 0.f;
    if (v >= 0) p = prob[((size_t)n * SP_ + s) * DCH + di];

    int pos = -1;
    unsigned long long unresolved = __ballot(v >= 0);
    while (unresolved) {
        const int src = __ffsll(unresolved) - 1;
        const int v0 = __shfl(v, src);
        const unsigned long long grp = __ballot(v == v0);
        int base = 0;
        if (lane == src) base = atomicAdd(&cur[v0], __popcll(grp));
        base = __shfl(base, src);
        if (v == v0) {
            const int rank = __popcll(grp & ((1ull << lane) - 1ull));
            pos = base + rank;
        }
        unresolved &= ~grp;
    }
    if (v >= 0)
        pk[pos] = make_int2((v << 13) | (n * SP_ + s), __float_as_int(p));
}

// ---------------- gather: chunk-per-wave segmented reduction ------------------
__global__ __launch_bounds__(256) void gather2_k(
    const int2* __restrict__ pk, const int* __restrict__ off,
    const float* __restrict__ ctxT, float* __restrict__ accT)
{
    const int gtid = blockIdx.x * 256 + threadIdx.x;
    const int wid = gtid >> 6;
    const int lane = threadIdx.x & 63;
    const int total = off[NVOX];
    const int lo = wid * CHUNK;
    if (lo >= total) return;
    const int hi = min(lo + CHUNK, total);
    float a0 = 0.f, a1 = 0.f;
    int2 e = pk[lo];
    for (int k = lo; k < hi; ++k) {
        const int2 en = (k + 1 < hi) ? pk[k + 1] : make_int2(-1, 0);
        const float p = __int_as_float(e.y);
        const int ns = e.x & 8191;
        const float* cb = ctxT + (size_t)ns * CCTX;
        a0 = fmaf(p, cb[lane], a0);
        if (lane < CCTX - 64) a1 = fmaf(p, cb[64 + lane], a1);
        if ((en.x >> 13) != (e.x >> 13)) {         // wave-uniform flush
            float* ab = accT + (size_t)(e.x >> 13) * CCTX;
            atomicAdd(ab + lane, a0);
            if (lane < CCTX - 64) atomicAdd(ab + 64 + lane, a1);
            a0 = a1 = 0.f;
        }
        e = en;
    }
}

// ---------------- transpose accT [v][c] -> out [c][v] ------------------------
__global__ void transpose_out_k(const float* __restrict__ accT, float* __restrict__ out) {
    const int idx = blockIdx.x * 256 + threadIdx.x;
    if (idx >= CCTX * NVOX) return;
    const int c = idx >> 14;
    const int v = idx & 16383;
    out[idx] = accT[(size_t)v * CCTX + c];
}

// ---------------- workspace layout (float offsets) ---------------------------
#define O_WHIA  512           // bf16 conv weights W2-A [32][9][512][16]
#define O_WHIB  1180160       // fp16 partial chunks 0-5 (during conv)
#define O_XT0   2359808       // 1,474,560  (chunked [n][32][960][16])
#define O_XT1   3834368       // 1,474,560; after s2: dprb/ctxT/1x1-wts home
#define O_XT2   5308928       // 1,474,560; W2-B buffer (whiC)
#define O_WD2B  6783488       // fp16 partial chunks 6-23 (overlap tail regions)
#define O_PK    8116736       // 946,176 (int2 x 473,088) -- after gemm
#define O_VIX   9062912       // 473,088
#define O_CNT   9536000       // 16,384   (ZBASE)
#define O_OFF   9552384       // 16,400
#define O_CUR   9568784       // 16,384
#define O_ACC   9585168       // 1,310,720
#define ZBASE   9536000
#define ZLEN4   339972        // (10,895,888 - 9,536,000) / 4
// xt1-region sublayout (after s2 consumes xt1):
#define XO_DPR  0             // 473,088 depth probs [n][s][112]
#define XO_CTX  473088        // 337,920 [n][s][80]
#define XO_WD2  946176        // 28,672 fl (bf16 112x512)
#define XO_WC2  974848        // 20,480 fl (bf16 80x512)
// end: 10,895,888 floats = 43.6 MB (unchanged)

extern "C" void kernel_launch(void* const* d_in, const int* in_sizes, int n_in,
                              void* d_out, int out_size, void* d_ws, size_t ws_size,
                              hipStream_t stream)
{
    const float* src  = (const float*)d_in[0];
    const float* w_s1 = (const float*)d_in[1];
    const float* w_s2 = (const float*)d_in[2];
    const float* w_d1 = (const float*)d_in[3];
    const float* w_d2 = (const float*)d_in[4];
    const float* b_d  = (const float*)d_in[5];
    const float* w_c1 = (const float*)d_in[6];
    const float* w_c2 = (const float*)d_in[7];
    const float* b_c  = (const float*)d_in[8];
    const float* s2e  = (const float*)d_in[9];
    const float* intr = (const float*)d_in[10];
    const float* ida  = (const float*)d_in[11];
    const float* bda  = (const float*)d_in[12];

    double* gc = (double*)d_ws;
    float* ws   = (float*)d_ws;
    short* whiA = (short*)(ws + O_WHIA);
    short* whiC = (short*)(ws + O_XT2);          // W2-B buffer (xt2 region)
    _Float16* pA = (_Float16*)(ws + O_WHIB);     // chunks 0-5
    _Float16* pB = (_Float16*)(ws + O_WD2B);     // chunks 6-23
    short* xt0  = (short*)(ws + O_XT0);
    short* xt1  = (short*)(ws + O_XT1);
    // xt1-region residents (valid after s2 consumed xt1):
    float* dprb = ws + O_XT1 + XO_DPR;
    float* ctxT = ws + O_XT1 + XO_CTX;
    short* wd2b = (short*)(ws + O_XT1 + XO_WD2);
    short* wc2b = (short*)(ws + O_XT1 + XO_WC2);
    int2*  pk   = (int2*)(ws + O_PK);
    int* vidx   = (int*)(ws + O_VIX);
    int* cnt    = (int*)(ws + O_CNT);
    int* offs   = (int*)(ws + O_OFF);
    int* cur    = (int*)(ws + O_CUR);
    float* accT = ws + O_ACC;
    float* out  = (float*)d_out;

    const int CMB = (NIMG * SP_ * CIN / 4 + 255) / 256;   // 2112 blocks

    // zero xt0+xt1 (contiguous; provides pad borders for s1/s2 halo reads)
    zero_k<<<(2949120 / 4 + 255) / 256, 256, 0, stream>>>((float4*)xt0, 2949120 / 4);

    geom_setup_k<<<1, 64, 0, stream>>>(s2e, intr, ida, bda, gc);
    src_to_xt_k<<<(NIMG * SP_ * CIN + 255) / 256, 256, 0, stream>>>(src, xt0);

    // s1+s2 weight convert (dual); s1: xt0 -> xt1; s2: xt1 -> xt0
    wsplit2_k<<<(2 * CIN * CIN) / 256, 256, 0, stream>>>(w_s1, whiA, w_s2, whiC);
    conv6_k<<<576, 256, 0, stream>>>(xt0, whiA, pA, pB);
    combine6_k<<<CMB, 256, 0, stream>>>(pA, pB, xt1);
    conv6_k<<<576, 256, 0, stream>>>(xt1, whiC, pA, pB);
    combine6_k<<<CMB, 256, 0, stream>>>(pA, pB, xt0);
    // c1+d1 weight convert (dual), then FUSED dual conv (K-split x2/layer).
    // Partials stay live through the gemm (no combine).
    wsplit2_k<<<(2 * CIN * CIN) / 256, 256, 0, stream>>>(w_c1, whiA, w_d1, whiC);
    conv6d_k<<<576, 256, 0, stream>>>(xt0, whiA, whiC, pA, pB);

    // 1x1 weights into the dead xt1 region (does NOT touch partial chunks)
    wsplit1_dual_k<<<((DCH + CCTX) * CIN + 255) / 256, 256, 0, stream>>>(
        w_d2, wd2b, w_c2, wc2b);
    // merged d2+c2 gemms reading fp16 partials directly; fused depth softmax.
    gemm1x1f_k<<<dim3(11, 2, NIMG), 256, 0, stream>>>(pA, pB,
                                                      wd2b, b_d, dprb,
                                                      wc2b, b_c, ctxT);

    // zero cnt/off/cur/accT AFTER gemm (chunks 21-23 overlapped this region)
    zero_k<<<(ZLEN4 + 255) / 256, 256, 0, stream>>>((float4*)(ws + ZBASE), ZLEN4);

    // binning
    point_voxel_k<<<(NPTS + 255) / 256, 256, 0, stream>>>(gc, vidx, cnt);
    prefix_k<<<1, 256, 0, stream>>>(cnt, offs, cur);
    fill_k<<<(NPTS + 255) / 256, 256, 0, stream>>>(vidx, dprb, cur, pk);

    // segmented-reduction gather
    {
        const int waves = (NPTS + CHUNK - 1) / CHUNK;
        const int blocks = (waves + 3) / 4;
        gather2_k<<<blocks, 256, 0, stream>>>(pk, offs, ctxT, accT);
    }
    transpose_out_k<<<(CCTX * NVOX + 255) / 256, 256, 0, stream>>>(accT, out);

    (void)in_sizes; (void)n_in; (void)out_size; (void)ws_size;
}